// Round 1
// baseline (1686.995 us; speedup 1.0000x reference)
//
#include <hip/hip_runtime.h>

#define DD 1024
#define HH 16
#define HDD 64
#define BBATCH 8
#define SS 1024
#define NROW (BBATCH*SS)   // 8192

// ---------------------------------------------------------------------------
// Kernel 1: fused QKV projection GEMM.
// grid = (D/64, NROW/64, 3), block = (16,16). z selects Wq/Wk/Wv.
// Writes q/k'/v in [B,H,S,HD] layout. For K: val = (x@Wk + bk)*scale + rel[t].
// ---------------------------------------------------------------------------
__global__ __launch_bounds__(256) void qkv_kernel(
    const float* __restrict__ x, const float* __restrict__ rel,
    const float* __restrict__ Wq, const float* __restrict__ bq,
    const float* __restrict__ Wk, const float* __restrict__ bk,
    const float* __restrict__ Wv, const float* __restrict__ bv,
    float* __restrict__ qws, float* __restrict__ kws, float* __restrict__ vws)
{
    __shared__ float As[16][68];   // [k][row], pad 68 -> 16B-aligned rows
    __shared__ float Bs[16][68];   // [k][col]

    const int z = blockIdx.z;
    const float* __restrict__ W    = (z == 0) ? Wq : (z == 1) ? Wk : Wv;
    const float* __restrict__ bias = (z == 0) ? bq : (z == 1) ? bk : bv;
    float* __restrict__ dst        = (z == 0) ? qws : (z == 1) ? kws : vws;

    const int tx = threadIdx.x, ty = threadIdx.y;
    const int tid = ty * 16 + tx;
    const int r0 = blockIdx.y * 64;
    const int c0 = blockIdx.x * 64;

    const int arow = tid >> 2, af = (tid & 3) * 4;     // A: 64 rows x 16 k
    const int bkr  = tid >> 4, bc = (tid & 15) * 4;    // B: 16 k x 64 cols

    float acc[4][4] = {};

    for (int k0 = 0; k0 < DD; k0 += 16) {
        float4 av  = *(const float4*)&x[(size_t)(r0 + arow) * DD + k0 + af];
        float4 bv4 = *(const float4*)&W[(size_t)(k0 + bkr) * DD + c0 + bc];
        __syncthreads();
        As[af + 0][arow] = av.x;
        As[af + 1][arow] = av.y;
        As[af + 2][arow] = av.z;
        As[af + 3][arow] = av.w;
        *(float4*)&Bs[bkr][bc] = bv4;
        __syncthreads();
        #pragma unroll
        for (int kk = 0; kk < 16; kk++) {
            float4 a4 = *(const float4*)&As[kk][ty * 4];
            float4 b4 = *(const float4*)&Bs[kk][tx * 4];
            const float* a = (const float*)&a4;
            const float* b = (const float*)&b4;
            #pragma unroll
            for (int ii = 0; ii < 4; ii++)
                #pragma unroll
                for (int jj = 0; jj < 4; jj++)
                    acc[ii][jj] = fmaf(a[ii], b[jj], acc[ii][jj]);
        }
    }

    // Epilogue. c0 is a multiple of 64 -> one head per column-tile.
    const int bb = r0 >> 10;         // batch
    const int h  = c0 >> 6;          // head
    const float scale = 0.125f;      // HD^-0.5
    #pragma unroll
    for (int ii = 0; ii < 4; ii++) {
        int r = r0 + ty * 4 + ii;
        int s = r & (SS - 1);
        float4 o; float* of = (float*)&o;
        #pragma unroll
        for (int jj = 0; jj < 4; jj++) {
            int c = c0 + tx * 4 + jj;
            float val = acc[ii][jj] + bias[c];
            if (z == 1) val = val * scale + rel[s * HDD + (tx * 4 + jj)];
            of[jj] = val;
        }
        size_t idx = (((size_t)bb * HH + h) * SS + s) * HDD + tx * 4;
        *(float4*)&dst[idx] = o;
    }
}

// ---------------------------------------------------------------------------
// Kernel 2: flash attention. grid = (S/64, H, B), block = (16,16).
// Per block: 64 queries x full K/V sweep with online softmax.
// k' already contains scale*k + rel, so scores = Qs . KVs^T directly.
// ---------------------------------------------------------------------------
__global__ __launch_bounds__(256) void attn_kernel(
    const float* __restrict__ qws, const float* __restrict__ kws,
    const float* __restrict__ vws, const int* __restrict__ mask,
    float* __restrict__ ctx)
{
    __shared__ float Qs[64][68];
    __shared__ float KVs[64][68];
    __shared__ float Ss[64][65];    // pad 65: conflict-free column access
    __shared__ float m_l[64], l_l[64], al_l[64], madd[64];

    const int qt = blockIdx.x, h = blockIdx.y, b = blockIdx.z;
    const int tx = threadIdx.x, ty = threadIdx.y;
    const int tid = ty * 16 + tx;
    const size_t base = ((size_t)b * HH + h) * SS;

    // load Q tile (64x64 floats)
    #pragma unroll
    for (int rep = 0; rep < 4; rep++) {
        int e = rep * 256 + tid;
        int i = e >> 4, f = (e & 15) * 4;
        *(float4*)&Qs[i][f] = *(const float4*)&qws[(base + qt * 64 + i) * HDD + f];
    }
    if (tid < 64) { m_l[tid] = -1e30f; l_l[tid] = 0.f; }
    float O[4][4] = {};
    __syncthreads();

    for (int kt = 0; kt < 16; kt++) {
        const int t0 = kt * 64;
        // ---- load K' tile + mask ----
        #pragma unroll
        for (int rep = 0; rep < 4; rep++) {
            int e = rep * 256 + tid;
            int j = e >> 4, f = (e & 15) * 4;
            *(float4*)&KVs[j][f] = *(const float4*)&kws[(base + t0 + j) * HDD + f];
        }
        if (tid < 64) madd[tid] = (mask[b * SS + t0 + tid] == 0) ? -1e30f : 0.0f;
        __syncthreads();

        // ---- scores: 64x64 = Q . K'^T ----
        float sc[4][4] = {};
        #pragma unroll 4
        for (int k4 = 0; k4 < 16; k4++) {
            float4 qa[4], kb[4];
            #pragma unroll
            for (int ii = 0; ii < 4; ii++) qa[ii] = *(const float4*)&Qs[ty * 4 + ii][k4 * 4];
            #pragma unroll
            for (int jj = 0; jj < 4; jj++) kb[jj] = *(const float4*)&KVs[tx * 4 + jj][k4 * 4];
            #pragma unroll
            for (int ii = 0; ii < 4; ii++) {
                const float* qf = (const float*)&qa[ii];
                #pragma unroll
                for (int jj = 0; jj < 4; jj++) {
                    const float* kf = (const float*)&kb[jj];
                    sc[ii][jj] = fmaf(qf[0], kf[0],
                                 fmaf(qf[1], kf[1],
                                 fmaf(qf[2], kf[2],
                                 fmaf(qf[3], kf[3], sc[ii][jj]))));
                }
            }
        }
        #pragma unroll
        for (int ii = 0; ii < 4; ii++)
            #pragma unroll
            for (int jj = 0; jj < 4; jj++)
                Ss[ty * 4 + ii][tx * 4 + jj] = sc[ii][jj] + madd[tx * 4 + jj];
        __syncthreads();

        // ---- online softmax row update (one thread per query row) ----
        if (tid < 64) {
            float mold = m_l[tid];
            float tmax = -1e30f;
            for (int j = 0; j < 64; j++) tmax = fmaxf(tmax, Ss[tid][j]);
            float mnew = fmaxf(mold, tmax);
            float alpha = __expf(mold - mnew);   // exact 1 if both -1e30; 0 on recovery
            float psum = 0.f;
            for (int j = 0; j < 64; j++) {
                float p = __expf(Ss[tid][j] - mnew);
                Ss[tid][j] = p;
                psum += p;
            }
            l_l[tid] = l_l[tid] * alpha + psum;
            m_l[tid] = mnew;
            al_l[tid] = alpha;
        }
        __syncthreads();

        // ---- rescale O, load V tile (K reads all done before last barrier) ----
        #pragma unroll
        for (int ii = 0; ii < 4; ii++) {
            float al = al_l[ty * 4 + ii];
            #pragma unroll
            for (int jj = 0; jj < 4; jj++) O[ii][jj] *= al;
        }
        #pragma unroll
        for (int rep = 0; rep < 4; rep++) {
            int e = rep * 256 + tid;
            int j = e >> 4, f = (e & 15) * 4;
            *(float4*)&KVs[j][f] = *(const float4*)&vws[(base + t0 + j) * HDD + f];
        }
        __syncthreads();

        // ---- O += P . V ----
        #pragma unroll 4
        for (int j = 0; j < 64; j++) {
            float4 vv = *(const float4*)&KVs[j][tx * 4];
            const float* vf = (const float*)&vv;
            #pragma unroll
            for (int ii = 0; ii < 4; ii++) {
                float p = Ss[ty * 4 + ii][j];
                #pragma unroll
                for (int jj = 0; jj < 4; jj++)
                    O[ii][jj] = fmaf(p, vf[jj], O[ii][jj]);
            }
        }
        __syncthreads();   // protects KVs/Ss overwrite next iteration
    }

    // ---- epilogue: normalize, write ctx in [B,S,D] layout ----
    #pragma unroll
    for (int ii = 0; ii < 4; ii++) {
        int i = ty * 4 + ii;
        float linv = 1.0f / l_l[i];
        int s = qt * 64 + i;
        float4 o; float* of = (float*)&o;
        #pragma unroll
        for (int jj = 0; jj < 4; jj++) of[jj] = O[ii][jj] * linv;
        *(float4*)&ctx[((size_t)b * SS + s) * DD + h * HDD + tx * 4] = o;
    }
}

// ---------------------------------------------------------------------------
// Kernel 3: output projection GEMM: out = ctx @ Wo + bo.
// grid = (D/64, NROW/64), block = (16,16).
// ---------------------------------------------------------------------------
__global__ __launch_bounds__(256) void out_kernel(
    const float* __restrict__ A, const float* __restrict__ W,
    const float* __restrict__ bias, float* __restrict__ out)
{
    __shared__ float As[16][68];
    __shared__ float Bs[16][68];

    const int tx = threadIdx.x, ty = threadIdx.y;
    const int tid = ty * 16 + tx;
    const int r0 = blockIdx.y * 64;
    const int c0 = blockIdx.x * 64;

    const int arow = tid >> 2, af = (tid & 3) * 4;
    const int bkr  = tid >> 4, bc = (tid & 15) * 4;

    float acc[4][4] = {};

    for (int k0 = 0; k0 < DD; k0 += 16) {
        float4 av  = *(const float4*)&A[(size_t)(r0 + arow) * DD + k0 + af];
        float4 bv4 = *(const float4*)&W[(size_t)(k0 + bkr) * DD + c0 + bc];
        __syncthreads();
        As[af + 0][arow] = av.x;
        As[af + 1][arow] = av.y;
        As[af + 2][arow] = av.z;
        As[af + 3][arow] = av.w;
        *(float4*)&Bs[bkr][bc] = bv4;
        __syncthreads();
        #pragma unroll
        for (int kk = 0; kk < 16; kk++) {
            float4 a4 = *(const float4*)&As[kk][ty * 4];
            float4 b4 = *(const float4*)&Bs[kk][tx * 4];
            const float* a = (const float*)&a4;
            const float* b = (const float*)&b4;
            #pragma unroll
            for (int ii = 0; ii < 4; ii++)
                #pragma unroll
                for (int jj = 0; jj < 4; jj++)
                    acc[ii][jj] = fmaf(a[ii], b[jj], acc[ii][jj]);
        }
    }

    #pragma unroll
    for (int ii = 0; ii < 4; ii++) {
        int r = r0 + ty * 4 + ii;
        float4 o; float* of = (float*)&o;
        #pragma unroll
        for (int jj = 0; jj < 4; jj++) {
            int c = c0 + tx * 4 + jj;
            of[jj] = acc[ii][jj] + bias[c];
        }
        *(float4*)&out[(size_t)r * DD + c0 + tx * 4] = o;
    }
}

extern "C" void kernel_launch(void* const* d_in, const int* in_sizes, int n_in,
                              void* d_out, int out_size, void* d_ws, size_t ws_size,
                              hipStream_t stream) {
    const float* x    = (const float*)d_in[0];
    const float* rel  = (const float*)d_in[1];
    const int*   mask = (const int*)d_in[2];
    const float* Wq = (const float*)d_in[3];  const float* bq = (const float*)d_in[4];
    const float* Wk = (const float*)d_in[5];  const float* bk = (const float*)d_in[6];
    const float* Wv = (const float*)d_in[7];  const float* bv = (const float*)d_in[8];
    const float* Wo = (const float*)d_in[9];  const float* bo = (const float*)d_in[10];
    float* out = (float*)d_out;

    float* ws = (float*)d_ws;
    const size_t NBUF = (size_t)BBATCH * SS * DD;   // 8,388,608 floats
    float* qws = ws;
    float* kws = ws + NBUF;
    float* vws = ws + 2 * NBUF;
    float* ctx = ws + 3 * NBUF;

    dim3 blk(16, 16);
    qkv_kernel<<<dim3(DD / 64, NROW / 64, 3), blk, 0, stream>>>(
        x, rel, Wq, bq, Wk, bk, Wv, bv, qws, kws, vws);
    attn_kernel<<<dim3(SS / 64, HH, BBATCH), blk, 0, stream>>>(
        qws, kws, vws, mask, ctx);
    out_kernel<<<dim3(DD / 64, NROW / 64), blk, 0, stream>>>(
        ctx, Wo, bo, out);
}

// Round 2
// 992.808 us; speedup vs baseline: 1.6992x; 1.6992x over previous
//
#include <hip/hip_runtime.h>

#define DD 1024
#define HH 16
#define HDD 64
#define BBATCH 8
#define SS 1024
#define NROW (BBATCH*SS)   // 8192

typedef __bf16 bf16x8 __attribute__((ext_vector_type(8)));
typedef float  f32x4  __attribute__((ext_vector_type(4)));

// ---- bf16 helpers (manual, RNE) ----
__device__ __forceinline__ unsigned short f2bf(float f) {
    unsigned u = __builtin_bit_cast(unsigned, f);
    u += 0x7fffu + ((u >> 16) & 1u);
    return (unsigned short)(u >> 16);
}
__device__ __forceinline__ float bf2f(unsigned short h) {
    unsigned u = ((unsigned)h) << 16;
    return __builtin_bit_cast(float, u);
}

// ---- async global->LDS 16B ----
__device__ __forceinline__ void async_cp16(const void* g, void* l) {
    __builtin_amdgcn_global_load_lds(
        (const __attribute__((address_space(1))) void*)g,
        (__attribute__((address_space(3))) void*)l, 16, 0, 0);
}

// ---------------------------------------------------------------------------
// Convert x (fp32) -> xh, xl (bf16 split). 8192 blocks x 256 thr x 4 elems.
// ---------------------------------------------------------------------------
__global__ __launch_bounds__(256) void conv_x_kernel(
    const float* __restrict__ x, unsigned short* __restrict__ xh,
    unsigned short* __restrict__ xl)
{
    size_t i4 = ((size_t)blockIdx.x * 256 + threadIdx.x) * 4;
    float4 v = *(const float4*)&x[i4];
    const float* vf = (const float*)&v;
    ushort4 hv, lv;
    unsigned short* hp = (unsigned short*)&hv;
    unsigned short* lp = (unsigned short*)&lv;
    #pragma unroll
    for (int c = 0; c < 4; c++) {
        unsigned short h = f2bf(vf[c]);
        hp[c] = h;
        lp[c] = f2bf(vf[c] - bf2f(h));
    }
    *(ushort4*)&xh[i4] = hv;
    *(ushort4*)&xl[i4] = lv;
}

// ---------------------------------------------------------------------------
// Transpose + split-convert weights: W[k][n] fp32 -> Wt[n][k] bf16 hi/lo.
// grid = (16,16,4): z picks Wq/Wk/Wv (-> wcat rows z*1024) or Wo (z==3).
// ---------------------------------------------------------------------------
__global__ __launch_bounds__(256) void conv_w_kernel(
    const float* __restrict__ Wq, const float* __restrict__ Wk,
    const float* __restrict__ Wv, const float* __restrict__ Wo,
    unsigned short* __restrict__ wth, unsigned short* __restrict__ wtl,
    unsigned short* __restrict__ woth, unsigned short* __restrict__ wotl)
{
    __shared__ float T[64][65];
    const int z = blockIdx.z;
    const float* src = (z == 0) ? Wq : (z == 1) ? Wk : (z == 2) ? Wv : Wo;
    unsigned short* dh = (z < 3) ? wth + (size_t)z * 1024 * 1024 : woth;
    unsigned short* dl = (z < 3) ? wtl + (size_t)z * 1024 * 1024 : wotl;
    const int k0 = blockIdx.x * 64, n0 = blockIdx.y * 64;
    const int tid = threadIdx.x;

    #pragma unroll
    for (int rep = 0; rep < 4; rep++) {
        int e = rep * 256 + tid;
        int kr = e >> 4, nc = (e & 15) * 4;
        *(float4*)&T[kr][nc] = *(const float4*)&src[(size_t)(k0 + kr) * 1024 + n0 + nc];
    }
    __syncthreads();
    #pragma unroll
    for (int rep = 0; rep < 4; rep++) {
        int e = rep * 256 + tid;
        int nr = e >> 4, kc = (e & 15) * 4;
        ushort4 hv, lv;
        unsigned short* hp = (unsigned short*)&hv;
        unsigned short* lp = (unsigned short*)&lv;
        #pragma unroll
        for (int c = 0; c < 4; c++) {
            float f = T[kc + c][nr];
            unsigned short h = f2bf(f);
            hp[c] = h;
            lp[c] = f2bf(f - bf2f(h));
        }
        size_t o = (size_t)(n0 + nr) * 1024 + k0 + kc;
        *(ushort4*)&dh[o] = hv;
        *(ushort4*)&dl[o] = lv;
    }
}

// ---------------------------------------------------------------------------
// Split-bf16 MFMA GEMM, 128x128 tile, BK=32, 3-term hi/lo.
// mode 0: qkv  — A = xh/xl [8192][1024], B = wcat_t [3072][1024],
//          grid (24,64); epilogue scatters to q/k/v [B,H,S,HD] fp32,
//          K-output gets (acc+bk)*scale + rel folded in.
// mode 1: out  — A = ctx hi/lo, B = wot [1024][1024], grid (8,64);
//          epilogue writes d_out fp32 + bo.
// ---------------------------------------------------------------------------
__global__ __launch_bounds__(256) void gemm_split(
    const unsigned short* __restrict__ Agh, const unsigned short* __restrict__ Agl,
    const unsigned short* __restrict__ Bgh, const unsigned short* __restrict__ Bgl,
    const float* __restrict__ b0, const float* __restrict__ b1,
    const float* __restrict__ b2, const float* __restrict__ rel,
    float* __restrict__ d0, float* __restrict__ d1, float* __restrict__ d2,
    int mode)
{
    __shared__ unsigned short smem[16384];        // 32 KB: 4 tiles of 128x32 bf16
    unsigned short* Ah = smem;
    unsigned short* Al = smem + 4096;
    unsigned short* Bh = smem + 8192;
    unsigned short* Bl = smem + 12288;

    const int tid = threadIdx.x;
    const int w = tid >> 6, l = tid & 63;
    const int lane15 = l & 15, quad = l >> 4;
    const int rm = (w >> 1) * 64, cn = (w & 1) * 64;
    const size_t r0 = (size_t)blockIdx.y * 128;
    const size_t n0 = (size_t)blockIdx.x * 128;

    const int lrow = l >> 2;           // row within 16-row chunk
    const int lko  = (l & 3) * 8;      // ushort offset within 32-elem row
    const int ch0 = 2 * w, ch1 = 2 * w + 1;

    f32x4 acc[4][4] = {};

    for (int ks = 0; ks < 32; ks++) {
        const size_t kofs = (size_t)ks * 32 + lko;
        __syncthreads();   // previous tile fully consumed
        {
            const size_t ga0 = (r0 + ch0 * 16 + lrow) * 1024 + kofs;
            const size_t ga1 = (r0 + ch1 * 16 + lrow) * 1024 + kofs;
            const size_t gb0 = (n0 + ch0 * 16 + lrow) * 1024 + kofs;
            const size_t gb1 = (n0 + ch1 * 16 + lrow) * 1024 + kofs;
            async_cp16(&Agh[ga0], &Ah[ch0 * 512]);
            async_cp16(&Agh[ga1], &Ah[ch1 * 512]);
            async_cp16(&Agl[ga0], &Al[ch0 * 512]);
            async_cp16(&Agl[ga1], &Al[ch1 * 512]);
            async_cp16(&Bgh[gb0], &Bh[ch0 * 512]);
            async_cp16(&Bgh[gb1], &Bh[ch1 * 512]);
            async_cp16(&Bgl[gb0], &Bl[ch0 * 512]);
            async_cp16(&Bgl[gb1], &Bl[ch1 * 512]);
        }
        __syncthreads();   // compiler drains vmcnt before barrier -> tile visible

        bf16x8 ah[4], al[4], bh[4], bl[4];
        #pragma unroll
        for (int ii = 0; ii < 4; ii++) {
            int ro = (rm + ii * 16 + lane15) * 32 + quad * 8;
            ah[ii] = *(const bf16x8*)&Ah[ro];
            al[ii] = *(const bf16x8*)&Al[ro];
        }
        #pragma unroll
        for (int jj = 0; jj < 4; jj++) {
            int co = (cn + jj * 16 + lane15) * 32 + quad * 8;
            bh[jj] = *(const bf16x8*)&Bh[co];
            bl[jj] = *(const bf16x8*)&Bl[co];
        }
        #pragma unroll
        for (int ii = 0; ii < 4; ii++)
            #pragma unroll
            for (int jj = 0; jj < 4; jj++) {
                f32x4 c = acc[ii][jj];
                c = __builtin_amdgcn_mfma_f32_16x16x32_bf16(ah[ii], bh[jj], c, 0, 0, 0);
                c = __builtin_amdgcn_mfma_f32_16x16x32_bf16(ah[ii], bl[jj], c, 0, 0, 0);
                c = __builtin_amdgcn_mfma_f32_16x16x32_bf16(al[ii], bh[jj], c, 0, 0, 0);
                acc[ii][jj] = c;
            }
    }

    // ---- epilogue ----
    if (mode == 0) {
        const int z = blockIdx.x >> 3;                 // 0=q, 1=k, 2=v
        const float* bias = (z == 0) ? b0 : (z == 1) ? b1 : b2;
        float* dst = (z == 0) ? d0 : (z == 1) ? d1 : d2;
        const int nbase = (blockIdx.x & 7) * 128 + cn; // col within 0..1023
        #pragma unroll
        for (int ii = 0; ii < 4; ii++)
            #pragma unroll
            for (int jj = 0; jj < 4; jj++) {
                int nc = nbase + jj * 16 + lane15;
                int h = nc >> 6, hd = nc & 63;
                float bsv = bias[nc];
                #pragma unroll
                for (int r = 0; r < 4; r++) {
                    int gr = (int)r0 + rm + ii * 16 + quad * 4 + r;
                    int b = gr >> 10, s = gr & 1023;
                    float val = acc[ii][jj][r] + bsv;
                    if (z == 1) val = val * 0.125f + rel[s * HDD + hd];
                    dst[(((size_t)b * HH + h) * SS + s) * HDD + hd] = val;
                }
            }
    } else {
        #pragma unroll
        for (int ii = 0; ii < 4; ii++)
            #pragma unroll
            for (int jj = 0; jj < 4; jj++) {
                int nc = (int)n0 + cn + jj * 16 + lane15;
                float bsv = b0[nc];
                #pragma unroll
                for (int r = 0; r < 4; r++) {
                    int gr = (int)r0 + rm + ii * 16 + quad * 4 + r;
                    d0[(size_t)gr * DD + nc] = acc[ii][jj][r] + bsv;
                }
            }
    }
}

// ---------------------------------------------------------------------------
// Flash attention (unchanged from round 1 except ctx output -> bf16 hi/lo).
// grid = (S/64, H, B), block = (16,16).
// ---------------------------------------------------------------------------
__global__ __launch_bounds__(256) void attn_kernel(
    const float* __restrict__ qws, const float* __restrict__ kws,
    const float* __restrict__ vws, const int* __restrict__ mask,
    unsigned short* __restrict__ ctxh, unsigned short* __restrict__ ctxl)
{
    __shared__ float Qs[64][68];
    __shared__ float KVs[64][68];
    __shared__ float Ss[64][65];
    __shared__ float m_l[64], l_l[64], al_l[64], madd[64];

    const int qt = blockIdx.x, hB = blockIdx.y, b = blockIdx.z;
    const int tx = threadIdx.x, ty = threadIdx.y;
    const int tid = ty * 16 + tx;
    const size_t base = ((size_t)b * HH + hB) * SS;

    #pragma unroll
    for (int rep = 0; rep < 4; rep++) {
        int e = rep * 256 + tid;
        int i = e >> 4, f = (e & 15) * 4;
        *(float4*)&Qs[i][f] = *(const float4*)&qws[(base + qt * 64 + i) * HDD + f];
    }
    if (tid < 64) { m_l[tid] = -1e30f; l_l[tid] = 0.f; }
    float O[4][4] = {};
    __syncthreads();

    for (int kt = 0; kt < 16; kt++) {
        const int t0 = kt * 64;
        #pragma unroll
        for (int rep = 0; rep < 4; rep++) {
            int e = rep * 256 + tid;
            int j = e >> 4, f = (e & 15) * 4;
            *(float4*)&KVs[j][f] = *(const float4*)&kws[(base + t0 + j) * HDD + f];
        }
        if (tid < 64) madd[tid] = (mask[b * SS + t0 + tid] == 0) ? -1e30f : 0.0f;
        __syncthreads();

        float sc[4][4] = {};
        #pragma unroll 4
        for (int k4 = 0; k4 < 16; k4++) {
            float4 qa[4], kb[4];
            #pragma unroll
            for (int ii = 0; ii < 4; ii++) qa[ii] = *(const float4*)&Qs[ty * 4 + ii][k4 * 4];
            #pragma unroll
            for (int jj = 0; jj < 4; jj++) kb[jj] = *(const float4*)&KVs[tx * 4 + jj][k4 * 4];
            #pragma unroll
            for (int ii = 0; ii < 4; ii++) {
                const float* qf = (const float*)&qa[ii];
                #pragma unroll
                for (int jj = 0; jj < 4; jj++) {
                    const float* kf = (const float*)&kb[jj];
                    sc[ii][jj] = fmaf(qf[0], kf[0],
                                 fmaf(qf[1], kf[1],
                                 fmaf(qf[2], kf[2],
                                 fmaf(qf[3], kf[3], sc[ii][jj]))));
                }
            }
        }
        #pragma unroll
        for (int ii = 0; ii < 4; ii++)
            #pragma unroll
            for (int jj = 0; jj < 4; jj++)
                Ss[ty * 4 + ii][tx * 4 + jj] = sc[ii][jj] + madd[tx * 4 + jj];
        __syncthreads();

        if (tid < 64) {
            float mold = m_l[tid];
            float tmax = -1e30f;
            for (int j = 0; j < 64; j++) tmax = fmaxf(tmax, Ss[tid][j]);
            float mnew = fmaxf(mold, tmax);
            float alpha = __expf(mold - mnew);
            float psum = 0.f;
            for (int j = 0; j < 64; j++) {
                float p = __expf(Ss[tid][j] - mnew);
                Ss[tid][j] = p;
                psum += p;
            }
            l_l[tid] = l_l[tid] * alpha + psum;
            m_l[tid] = mnew;
            al_l[tid] = alpha;
        }
        __syncthreads();

        #pragma unroll
        for (int ii = 0; ii < 4; ii++) {
            float al = al_l[ty * 4 + ii];
            #pragma unroll
            for (int jj = 0; jj < 4; jj++) O[ii][jj] *= al;
        }
        #pragma unroll
        for (int rep = 0; rep < 4; rep++) {
            int e = rep * 256 + tid;
            int j = e >> 4, f = (e & 15) * 4;
            *(float4*)&KVs[j][f] = *(const float4*)&vws[(base + t0 + j) * HDD + f];
        }
        __syncthreads();

        #pragma unroll 4
        for (int j = 0; j < 64; j++) {
            float4 vv = *(const float4*)&KVs[j][tx * 4];
            const float* vf = (const float*)&vv;
            #pragma unroll
            for (int ii = 0; ii < 4; ii++) {
                float p = Ss[ty * 4 + ii][j];
                #pragma unroll
                for (int jj = 0; jj < 4; jj++)
                    O[ii][jj] = fmaf(p, vf[jj], O[ii][jj]);
            }
        }
        __syncthreads();
    }

    #pragma unroll
    for (int ii = 0; ii < 4; ii++) {
        int i = ty * 4 + ii;
        float linv = 1.0f / l_l[i];
        int s = qt * 64 + i;
        ushort4 hv, lv;
        unsigned short* hp = (unsigned short*)&hv;
        unsigned short* lp = (unsigned short*)&lv;
        #pragma unroll
        for (int jj = 0; jj < 4; jj++) {
            float val = O[ii][jj] * linv;
            unsigned short h = f2bf(val);
            hp[jj] = h;
            lp[jj] = f2bf(val - bf2f(h));
        }
        size_t cidx = ((size_t)b * SS + s) * DD + hB * HDD + tx * 4;
        *(ushort4*)&ctxh[cidx] = hv;
        *(ushort4*)&ctxl[cidx] = lv;
    }
}

extern "C" void kernel_launch(void* const* d_in, const int* in_sizes, int n_in,
                              void* d_out, int out_size, void* d_ws, size_t ws_size,
                              hipStream_t stream) {
    const float* x    = (const float*)d_in[0];
    const float* rel  = (const float*)d_in[1];
    const int*   mask = (const int*)d_in[2];
    const float* Wq = (const float*)d_in[3];  const float* bq = (const float*)d_in[4];
    const float* Wk = (const float*)d_in[5];  const float* bk = (const float*)d_in[6];
    const float* Wv = (const float*)d_in[7];  const float* bv = (const float*)d_in[8];
    const float* Wo = (const float*)d_in[9];  const float* bo = (const float*)d_in[10];
    float* out = (float*)d_out;

    const size_t XN = (size_t)NROW * DD;   // 8,388,608
    char* p = (char*)d_ws;
    unsigned short* xh  = (unsigned short*)p; p += XN * 2;
    unsigned short* xl  = (unsigned short*)p; p += XN * 2;
    unsigned short* wth = (unsigned short*)p; p += (size_t)3072 * 1024 * 2;
    unsigned short* wtl = (unsigned short*)p; p += (size_t)3072 * 1024 * 2;
    unsigned short* woth= (unsigned short*)p; p += (size_t)1024 * 1024 * 2;
    unsigned short* wotl= (unsigned short*)p; p += (size_t)1024 * 1024 * 2;
    float* qws = (float*)p; p += XN * 4;
    float* kws = (float*)p; p += XN * 4;
    float* vws = (float*)p; p += XN * 4;
    // ctx aliases x-split buffers (x dead after qkv gemm)
    unsigned short* ctxh = xh;
    unsigned short* ctxl = xl;

    conv_x_kernel<<<dim3((unsigned)(XN / 1024)), 256, 0, stream>>>(x, xh, xl);
    conv_w_kernel<<<dim3(16, 16, 4), 256, 0, stream>>>(Wq, Wk, Wv, Wo, wth, wtl, woth, wotl);
    gemm_split<<<dim3(24, 64), 256, 0, stream>>>(
        xh, xl, wth, wtl, bq, bk, bv, rel, qws, kws, vws, 0);
    attn_kernel<<<dim3(SS / 64, HH, BBATCH), dim3(16, 16), 0, stream>>>(
        qws, kws, vws, mask, ctxh, ctxl);
    gemm_split<<<dim3(8, 64), 256, 0, stream>>>(
        ctxh, ctxl, woth, wotl, bo, nullptr, nullptr, nullptr, out, nullptr, nullptr, 1);
}

// Round 3
// 493.477 us; speedup vs baseline: 3.4186x; 2.0119x over previous
//
#include <hip/hip_runtime.h>

#define DD 1024
#define HH 16
#define HDD 64
#define BBATCH 8
#define SS 1024
#define NROW (BBATCH*SS)   // 8192
#define PSTR 72            // LDS row stride (ushorts) for attn tiles: 144B, bank-minimal

typedef __bf16 bf16x8 __attribute__((ext_vector_type(8)));
typedef float  f32x4  __attribute__((ext_vector_type(4)));
typedef unsigned short u16x8 __attribute__((ext_vector_type(8)));

// ---- bf16 helpers (manual, RNE) ----
__device__ __forceinline__ unsigned short f2bf(float f) {
    unsigned u = __builtin_bit_cast(unsigned, f);
    u += 0x7fffu + ((u >> 16) & 1u);
    return (unsigned short)(u >> 16);
}
__device__ __forceinline__ float bf2f(unsigned short h) {
    unsigned u = ((unsigned)h) << 16;
    return __builtin_bit_cast(float, u);
}

// ---- async global->LDS 16B ----
__device__ __forceinline__ void async_cp16(const void* g, void* l) {
    __builtin_amdgcn_global_load_lds(
        (const __attribute__((address_space(1))) void*)g,
        (__attribute__((address_space(3))) void*)l, 16, 0, 0);
}

// ---------------------------------------------------------------------------
// Convert x (fp32) -> xh, xl (bf16 split). 8192 blocks x 256 thr x 4 elems.
// ---------------------------------------------------------------------------
__global__ __launch_bounds__(256) void conv_x_kernel(
    const float* __restrict__ x, unsigned short* __restrict__ xh,
    unsigned short* __restrict__ xl)
{
    size_t i4 = ((size_t)blockIdx.x * 256 + threadIdx.x) * 4;
    float4 v = *(const float4*)&x[i4];
    const float* vf = (const float*)&v;
    ushort4 hv, lv;
    unsigned short* hp = (unsigned short*)&hv;
    unsigned short* lp = (unsigned short*)&lv;
    #pragma unroll
    for (int c = 0; c < 4; c++) {
        unsigned short h = f2bf(vf[c]);
        hp[c] = h;
        lp[c] = f2bf(vf[c] - bf2f(h));
    }
    *(ushort4*)&xh[i4] = hv;
    *(ushort4*)&xl[i4] = lv;
}

// ---------------------------------------------------------------------------
// Transpose + split-convert weights: W[k][n] fp32 -> Wt[n][k] bf16 hi/lo.
// ---------------------------------------------------------------------------
__global__ __launch_bounds__(256) void conv_w_kernel(
    const float* __restrict__ Wq, const float* __restrict__ Wk,
    const float* __restrict__ Wv, const float* __restrict__ Wo,
    unsigned short* __restrict__ wth, unsigned short* __restrict__ wtl,
    unsigned short* __restrict__ woth, unsigned short* __restrict__ wotl)
{
    __shared__ float T[64][65];
    const int z = blockIdx.z;
    const float* src = (z == 0) ? Wq : (z == 1) ? Wk : (z == 2) ? Wv : Wo;
    unsigned short* dh = (z < 3) ? wth + (size_t)z * 1024 * 1024 : woth;
    unsigned short* dl = (z < 3) ? wtl + (size_t)z * 1024 * 1024 : wotl;
    const int k0 = blockIdx.x * 64, n0 = blockIdx.y * 64;
    const int tid = threadIdx.x;

    #pragma unroll
    for (int rep = 0; rep < 4; rep++) {
        int e = rep * 256 + tid;
        int kr = e >> 4, nc = (e & 15) * 4;
        *(float4*)&T[kr][nc] = *(const float4*)&src[(size_t)(k0 + kr) * 1024 + n0 + nc];
    }
    __syncthreads();
    #pragma unroll
    for (int rep = 0; rep < 4; rep++) {
        int e = rep * 256 + tid;
        int nr = e >> 4, kc = (e & 15) * 4;
        ushort4 hv, lv;
        unsigned short* hp = (unsigned short*)&hv;
        unsigned short* lp = (unsigned short*)&lv;
        #pragma unroll
        for (int c = 0; c < 4; c++) {
            float f = T[kc + c][nr];
            unsigned short h = f2bf(f);
            hp[c] = h;
            lp[c] = f2bf(f - bf2f(h));
        }
        size_t o = (size_t)(n0 + nr) * 1024 + k0 + kc;
        *(ushort4*)&dh[o] = hv;
        *(ushort4*)&dl[o] = lv;
    }
}

// ---------------------------------------------------------------------------
// Split-bf16 MFMA GEMM, 128x128 tile, BK=32, 3-term hi/lo.
// mode 0: qkv — epilogue writes qh/ql (bf16 split), kh = (acc+bk)*scale+rel
//          (bf16), vt = V transposed [B,H,HD,S] (bf16).
// mode 1: out — ctx hi/lo @ WoT + bo -> d_out fp32.
// ---------------------------------------------------------------------------
__global__ __launch_bounds__(256) void gemm_split(
    const unsigned short* __restrict__ Agh, const unsigned short* __restrict__ Agl,
    const unsigned short* __restrict__ Bgh, const unsigned short* __restrict__ Bgl,
    const float* __restrict__ b0, const float* __restrict__ b1,
    const float* __restrict__ b2, const float* __restrict__ rel,
    unsigned short* __restrict__ oqh, unsigned short* __restrict__ oql,
    unsigned short* __restrict__ okh, unsigned short* __restrict__ ovt,
    float* __restrict__ dOut, int mode)
{
    __shared__ unsigned short smem[16384];        // 32 KB
    unsigned short* Ah = smem;
    unsigned short* Al = smem + 4096;
    unsigned short* Bh = smem + 8192;
    unsigned short* Bl = smem + 12288;

    const int tid = threadIdx.x;
    const int w = tid >> 6, l = tid & 63;
    const int lane15 = l & 15, quad = l >> 4;
    const int rm = (w >> 1) * 64, cn = (w & 1) * 64;
    const size_t r0 = (size_t)blockIdx.y * 128;
    const size_t n0 = (size_t)blockIdx.x * 128;

    const int lrow = l >> 2;
    const int lko  = (l & 3) * 8;
    const int ch0 = 2 * w, ch1 = 2 * w + 1;

    f32x4 acc[4][4] = {};

    for (int ks = 0; ks < 32; ks++) {
        const size_t kofs = (size_t)ks * 32 + lko;
        __syncthreads();
        {
            const size_t ga0 = (r0 + ch0 * 16 + lrow) * 1024 + kofs;
            const size_t ga1 = (r0 + ch1 * 16 + lrow) * 1024 + kofs;
            const size_t gb0 = (n0 + ch0 * 16 + lrow) * 1024 + kofs;
            const size_t gb1 = (n0 + ch1 * 16 + lrow) * 1024 + kofs;
            async_cp16(&Agh[ga0], &Ah[ch0 * 512]);
            async_cp16(&Agh[ga1], &Ah[ch1 * 512]);
            async_cp16(&Agl[ga0], &Al[ch0 * 512]);
            async_cp16(&Agl[ga1], &Al[ch1 * 512]);
            async_cp16(&Bgh[gb0], &Bh[ch0 * 512]);
            async_cp16(&Bgh[gb1], &Bh[ch1 * 512]);
            async_cp16(&Bgl[gb0], &Bl[ch0 * 512]);
            async_cp16(&Bgl[gb1], &Bl[ch1 * 512]);
        }
        __syncthreads();

        bf16x8 ah[4], al[4], bh4[4], bl4[4];
        #pragma unroll
        for (int ii = 0; ii < 4; ii++) {
            int ro = (rm + ii * 16 + lane15) * 32 + quad * 8;
            ah[ii] = *(const bf16x8*)&Ah[ro];
            al[ii] = *(const bf16x8*)&Al[ro];
        }
        #pragma unroll
        for (int jj = 0; jj < 4; jj++) {
            int co = (cn + jj * 16 + lane15) * 32 + quad * 8;
            bh4[jj] = *(const bf16x8*)&Bh[co];
            bl4[jj] = *(const bf16x8*)&Bl[co];
        }
        #pragma unroll
        for (int ii = 0; ii < 4; ii++)
            #pragma unroll
            for (int jj = 0; jj < 4; jj++) {
                f32x4 c = acc[ii][jj];
                c = __builtin_amdgcn_mfma_f32_16x16x32_bf16(ah[ii], bh4[jj], c, 0, 0, 0);
                c = __builtin_amdgcn_mfma_f32_16x16x32_bf16(ah[ii], bl4[jj], c, 0, 0, 0);
                c = __builtin_amdgcn_mfma_f32_16x16x32_bf16(al[ii], bh4[jj], c, 0, 0, 0);
                acc[ii][jj] = c;
            }
    }

    if (mode == 0) {
        const int z = blockIdx.x >> 3;                 // 0=q, 1=k, 2=v
        const float* bias = (z == 0) ? b0 : (z == 1) ? b1 : b2;
        const int nbase = (blockIdx.x & 7) * 128 + cn;
        #pragma unroll
        for (int ii = 0; ii < 4; ii++)
            #pragma unroll
            for (int jj = 0; jj < 4; jj++) {
                int nc = nbase + jj * 16 + lane15;
                int hh = nc >> 6, hd = nc & 63;
                float bsv = bias[nc];
                #pragma unroll
                for (int r = 0; r < 4; r++) {
                    int gr = (int)r0 + rm + ii * 16 + quad * 4 + r;
                    int bb = gr >> 10, s = gr & 1023;
                    float val = acc[ii][jj][r] + bsv;
                    size_t hidx = (((size_t)bb * HH + hh) * SS + s) * HDD + hd;
                    if (z == 0) {
                        unsigned short hi = f2bf(val);
                        oqh[hidx] = hi;
                        oql[hidx] = f2bf(val - bf2f(hi));
                    } else if (z == 1) {
                        val = val * 0.125f + rel[s * HDD + hd];
                        okh[hidx] = f2bf(val);
                    } else {
                        ovt[(((size_t)bb * HH + hh) * HDD + hd) * SS + s] = f2bf(val);
                    }
                }
            }
    } else {
        #pragma unroll
        for (int ii = 0; ii < 4; ii++)
            #pragma unroll
            for (int jj = 0; jj < 4; jj++) {
                int nc = (int)n0 + cn + jj * 16 + lane15;
                float bsv = b0[nc];
                #pragma unroll
                for (int r = 0; r < 4; r++) {
                    int gr = (int)r0 + rm + ii * 16 + quad * 4 + r;
                    dOut[(size_t)gr * DD + nc] = acc[ii][jj][r] + bsv;
                }
            }
    }
}

// ---------------------------------------------------------------------------
// MFMA flash attention. grid = 1024 linear (id = qt*128 + bh for XCD
// locality: all 8 q-tiles of one (b,h) share an XCD). block = 256 (4 waves),
// each wave owns 32 query rows (2 m-tiles).
// ---------------------------------------------------------------------------
__global__ __launch_bounds__(256) void attn_mfma(
    const unsigned short* __restrict__ qh, const unsigned short* __restrict__ ql,
    const unsigned short* __restrict__ kh, const unsigned short* __restrict__ vt,
    const int* __restrict__ mask,
    unsigned short* __restrict__ ctxh, unsigned short* __restrict__ ctxl)
{
    __shared__ unsigned short Ks[64 * PSTR];   // [key][d]   9216 B
    __shared__ unsigned short Vs[64 * PSTR];   // [d][key]   9216 B
    __shared__ unsigned short Ps[128 * PSTR];  // [qrow][key swizzled] 18432 B

    const int tid = threadIdx.x;
    const int w = tid >> 6, l = tid & 63;
    const int lane15 = l & 15, quad = l >> 4;
    const int id = blockIdx.x;
    const int qt = id >> 7;          // 0..7
    const int bh = id & 127;
    const int b = bh >> 4, h = bh & 15;
    const size_t kbase0 = (size_t)bh * SS;     // key-row base in [B*H*S]
    const size_t vbase0 = (size_t)bh * HDD;    // d-row base in [B*H*HD]
    const size_t qrow0 = kbase0 + qt * 128 + w * 32;

    // resident Q fragments (A-layout): [mtile][kstep], hi/lo
    bf16x8 qfh[2][2], qfl[2][2];
    #pragma unroll
    for (int mi = 0; mi < 2; mi++)
        #pragma unroll
        for (int ks = 0; ks < 2; ks++) {
            size_t off = (qrow0 + mi * 16 + lane15) * HDD + ks * 32 + quad * 8;
            qfh[mi][ks] = *(const bf16x8*)&qh[off];
            qfl[mi][ks] = *(const bf16x8*)&ql[off];
        }

    f32x4 O[2][4] = {};                  // [mtile][d-tile]
    float m_s[2][4], l_s[2][4];
    #pragma unroll
    for (int mi = 0; mi < 2; mi++)
        #pragma unroll
        for (int r = 0; r < 4; r++) { m_s[mi][r] = -1e30f; l_s[mi][r] = 0.f; }

    for (int kt = 0; kt < 16; kt++) {
        const int t0 = kt * 64;
        __syncthreads();   // all waves done reading Ks/Vs from previous iter
        // ---- stage K' tile [64 keys][64 d] and V tile [64 d][64 keys] ----
        #pragma unroll
        for (int rep = 0; rep < 2; rep++) {
            int c = rep * 256 + tid;            // 0..511
            int row = c >> 3, cc = (c & 7) * 8;
            u16x8 tk = *(const u16x8*)&kh[(kbase0 + t0 + row) * HDD + cc];
            u16x8 tv = *(const u16x8*)&vt[(vbase0 + row) * SS + t0 + cc];
            *(u16x8*)&Ks[row * PSTR + cc] = tk;
            *(u16x8*)&Vs[row * PSTR + cc] = tv;
        }
        __syncthreads();

        float madd[4];
        #pragma unroll
        for (int nt = 0; nt < 4; nt++)
            madd[nt] = (mask[b * SS + t0 + nt * 16 + lane15] == 0) ? -1e30f : 0.0f;

        #pragma unroll
        for (int mi = 0; mi < 2; mi++) {
            // ---- scores: 16 q-rows x 64 keys ----
            f32x4 S[4] = {};
            #pragma unroll
            for (int nt = 0; nt < 4; nt++) {
                bf16x8 kf0 = *(const bf16x8*)&Ks[(nt * 16 + lane15) * PSTR + quad * 8];
                bf16x8 kf1 = *(const bf16x8*)&Ks[(nt * 16 + lane15) * PSTR + 32 + quad * 8];
                f32x4 c = S[nt];
                c = __builtin_amdgcn_mfma_f32_16x16x32_bf16(qfh[mi][0], kf0, c, 0, 0, 0);
                c = __builtin_amdgcn_mfma_f32_16x16x32_bf16(qfl[mi][0], kf0, c, 0, 0, 0);
                c = __builtin_amdgcn_mfma_f32_16x16x32_bf16(qfh[mi][1], kf1, c, 0, 0, 0);
                c = __builtin_amdgcn_mfma_f32_16x16x32_bf16(qfl[mi][1], kf1, c, 0, 0, 0);
                S[nt] = c;
            }
            #pragma unroll
            for (int nt = 0; nt < 4; nt++)
                #pragma unroll
                for (int r = 0; r < 4; r++) S[nt][r] += madd[nt];

            // ---- online softmax (rows = quad*4+r, cols = lane15) ----
            float tm[4];
            #pragma unroll
            for (int r = 0; r < 4; r++)
                tm[r] = fmaxf(fmaxf(S[0][r], S[1][r]), fmaxf(S[2][r], S[3][r]));
            #pragma unroll
            for (int st = 1; st < 16; st <<= 1)
                #pragma unroll
                for (int r = 0; r < 4; r++)
                    tm[r] = fmaxf(tm[r], __shfl_xor(tm[r], st, 64));
            float alpha[4];
            #pragma unroll
            for (int r = 0; r < 4; r++) {
                float mn = fmaxf(m_s[mi][r], tm[r]);
                alpha[r] = __expf(m_s[mi][r] - mn);
                m_s[mi][r] = mn;
            }
            float ps[4] = {0.f, 0.f, 0.f, 0.f};
            #pragma unroll
            for (int nt = 0; nt < 4; nt++)
                #pragma unroll
                for (int r = 0; r < 4; r++) {
                    float p = __expf(S[nt][r] - m_s[mi][r]);
                    S[nt][r] = p;
                    ps[r] += p;
                }
            #pragma unroll
            for (int st = 1; st < 16; st <<= 1)
                #pragma unroll
                for (int r = 0; r < 4; r++)
                    ps[r] += __shfl_xor(ps[r], st, 64);
            #pragma unroll
            for (int r = 0; r < 4; r++)
                l_s[mi][r] = l_s[mi][r] * alpha[r] + ps[r];
            // rescale O
            #pragma unroll
            for (int nd = 0; nd < 4; nd++)
                #pragma unroll
                for (int r = 0; r < 4; r++) O[mi][nd][r] *= alpha[r];
            // ---- write P (bf16) to wave-private LDS, swizzled col +16*quad ----
            const int rowb = w * 32 + mi * 16 + quad * 4;
            #pragma unroll
            for (int nt = 0; nt < 4; nt++) {
                int colp = (nt * 16 + lane15 + 16 * quad) & 63;
                #pragma unroll
                for (int r = 0; r < 4; r++)
                    Ps[(rowb + r) * PSTR + colp] = f2bf(S[nt][r]);
            }
        }

        // ---- PV: O += P . V ----
        const int swz = 16 * (lane15 >> 2);
        #pragma unroll
        for (int ks2 = 0; ks2 < 2; ks2++) {
            bf16x8 pf[2];
            #pragma unroll
            for (int mi = 0; mi < 2; mi++) {
                int colp = (ks2 * 32 + quad * 8 + swz) & 63;
                pf[mi] = *(const bf16x8*)&Ps[(w * 32 + mi * 16 + lane15) * PSTR + colp];
            }
            #pragma unroll
            for (int nd = 0; nd < 4; nd++) {
                bf16x8 vf = *(const bf16x8*)&Vs[(nd * 16 + lane15) * PSTR + ks2 * 32 + quad * 8];
                #pragma unroll
                for (int mi = 0; mi < 2; mi++)
                    O[mi][nd] = __builtin_amdgcn_mfma_f32_16x16x32_bf16(pf[mi], vf, O[mi][nd], 0, 0, 0);
            }
        }
    }

    // ---- epilogue: normalize, split to bf16 hi/lo ctx [B,S,D] ----
    #pragma unroll
    for (int mi = 0; mi < 2; mi++) {
        float linv[4];
        #pragma unroll
        for (int r = 0; r < 4; r++) linv[r] = 1.0f / l_s[mi][r];
        #pragma unroll
        for (int nd = 0; nd < 4; nd++) {
            int d = nd * 16 + lane15;
            #pragma unroll
            for (int r = 0; r < 4; r++) {
                int srow = qt * 128 + w * 32 + mi * 16 + quad * 4 + r;
                float val = O[mi][nd][r] * linv[r];
                unsigned short hi = f2bf(val);
                size_t idx = ((size_t)b * SS + srow) * DD + h * HDD + d;
                ctxh[idx] = hi;
                ctxl[idx] = f2bf(val - bf2f(hi));
            }
        }
    }
}

extern "C" void kernel_launch(void* const* d_in, const int* in_sizes, int n_in,
                              void* d_out, int out_size, void* d_ws, size_t ws_size,
                              hipStream_t stream) {
    const float* x    = (const float*)d_in[0];
    const float* rel  = (const float*)d_in[1];
    const int*   mask = (const int*)d_in[2];
    const float* Wq = (const float*)d_in[3];  const float* bq = (const float*)d_in[4];
    const float* Wk = (const float*)d_in[5];  const float* bk = (const float*)d_in[6];
    const float* Wv = (const float*)d_in[7];  const float* bv = (const float*)d_in[8];
    const float* Wo = (const float*)d_in[9];  const float* bo = (const float*)d_in[10];
    float* out = (float*)d_out;

    const size_t XN = (size_t)NROW * DD;   // 8,388,608
    char* p = (char*)d_ws;
    unsigned short* xh  = (unsigned short*)p; p += XN * 2;
    unsigned short* xl  = (unsigned short*)p; p += XN * 2;
    unsigned short* wth = (unsigned short*)p; p += (size_t)3072 * 1024 * 2;
    unsigned short* wtl = (unsigned short*)p; p += (size_t)3072 * 1024 * 2;
    unsigned short* woth= (unsigned short*)p; p += (size_t)1024 * 1024 * 2;
    unsigned short* wotl= (unsigned short*)p; p += (size_t)1024 * 1024 * 2;
    unsigned short* qhp = (unsigned short*)p; p += XN * 2;
    unsigned short* qlp = (unsigned short*)p; p += XN * 2;
    unsigned short* khp = (unsigned short*)p; p += XN * 2;
    unsigned short* vtp = (unsigned short*)p; p += XN * 2;
    // ctx aliases x-split buffers (x dead after qkv gemm)
    unsigned short* ctxh = xh;
    unsigned short* ctxl = xl;

    conv_x_kernel<<<dim3((unsigned)(XN / 1024)), 256, 0, stream>>>(x, xh, xl);
    conv_w_kernel<<<dim3(16, 16, 4), 256, 0, stream>>>(Wq, Wk, Wv, Wo, wth, wtl, woth, wotl);
    gemm_split<<<dim3(24, 64), 256, 0, stream>>>(
        xh, xl, wth, wtl, bq, bk, bv, rel,
        qhp, qlp, khp, vtp, nullptr, 0);
    attn_mfma<<<dim3(1024), 256, 0, stream>>>(
        qhp, qlp, khp, vtp, mask, ctxh, ctxl);
    gemm_split<<<dim3(8, 64), 256, 0, stream>>>(
        ctxh, ctxl, woth, wotl, bo, nullptr, nullptr, nullptr,
        nullptr, nullptr, nullptr, nullptr, out, 1);
}

// Round 4
// 452.700 us; speedup vs baseline: 3.7265x; 1.0901x over previous
//
#include <hip/hip_runtime.h>

#define DD 1024
#define HH 16
#define HDD 64
#define BBATCH 8
#define SS 1024
#define NROW (BBATCH*SS)   // 8192
#define PSTR 72            // LDS row stride (halfs) for attn tiles

typedef _Float16 f16x8 __attribute__((ext_vector_type(8)));
typedef _Float16 f16x4 __attribute__((ext_vector_type(4)));
typedef float    f32x4 __attribute__((ext_vector_type(4)));

// ---- async global->LDS 16B ----
__device__ __forceinline__ void async_cp16(const void* g, void* l) {
    __builtin_amdgcn_global_load_lds(
        (const __attribute__((address_space(1))) void*)g,
        (__attribute__((address_space(3))) void*)l, 16, 0, 0);
}

// ---------------------------------------------------------------------------
// Convert x (fp32) -> xh, xl (fp16 split). 4096 blocks x 256 thr x 8 elems.
// ---------------------------------------------------------------------------
__global__ __launch_bounds__(256) void conv_x_kernel(
    const float* __restrict__ x, _Float16* __restrict__ xh,
    _Float16* __restrict__ xl)
{
    size_t i8 = ((size_t)blockIdx.x * 256 + threadIdx.x) * 8;
    float4 v0 = *(const float4*)&x[i8];
    float4 v1 = *(const float4*)&x[i8 + 4];
    float vf[8] = {v0.x, v0.y, v0.z, v0.w, v1.x, v1.y, v1.z, v1.w};
    f16x8 hv, lv;
    #pragma unroll
    for (int c = 0; c < 8; c++) {
        _Float16 h = (_Float16)vf[c];
        hv[c] = h;
        lv[c] = (_Float16)(vf[c] - (float)h);
    }
    *(f16x8*)&xh[i8] = hv;
    *(f16x8*)&xl[i8] = lv;
}

// ---------------------------------------------------------------------------
// Transpose + convert weights: W[k][n] fp32 -> Wt[n][k] fp16.
// grid = (16,16,4): z in {Wq,Wk,Wv -> wt rows z*1024, Wo -> wot}.
// ---------------------------------------------------------------------------
__global__ __launch_bounds__(256) void conv_w_kernel(
    const float* __restrict__ Wq, const float* __restrict__ Wk,
    const float* __restrict__ Wv, const float* __restrict__ Wo,
    _Float16* __restrict__ wt, _Float16* __restrict__ wot)
{
    __shared__ float T[64][65];
    const int z = blockIdx.z;
    const float* src = (z == 0) ? Wq : (z == 1) ? Wk : (z == 2) ? Wv : Wo;
    _Float16* dh = (z < 3) ? wt + (size_t)z * 1024 * 1024 : wot;
    const int k0 = blockIdx.x * 64, n0 = blockIdx.y * 64;
    const int tid = threadIdx.x;

    #pragma unroll
    for (int rep = 0; rep < 4; rep++) {
        int e = rep * 256 + tid;
        int kr = e >> 4, nc = (e & 15) * 4;
        *(float4*)&T[kr][nc] = *(const float4*)&src[(size_t)(k0 + kr) * 1024 + n0 + nc];
    }
    __syncthreads();
    #pragma unroll
    for (int rep = 0; rep < 4; rep++) {
        int e = rep * 256 + tid;
        int nr = e >> 4, kc = (e & 15) * 4;
        f16x4 hv;
        #pragma unroll
        for (int c = 0; c < 4; c++) hv[c] = (_Float16)T[kc + c][nr];
        *(f16x4*)&dh[(size_t)(n0 + nr) * 1024 + k0 + kc] = hv;
    }
}

// ---------------------------------------------------------------------------
// 2-term split-fp16 MFMA GEMM, 128x128 tile, BK=32: C = (Ah+Al)·B^T.
// mode 0: qkv — A = xh/xl, B = wt[3072][1024]; epilogue: q fp16,
//          k' = (acc+bk)*scale+rel fp16, v transposed [B,H,HD,S] fp16.
// mode 1: out — A = ctx hi/lo, B = wot; epilogue: d_out fp32 + bo.
// ---------------------------------------------------------------------------
__global__ __launch_bounds__(256) void gemm_split(
    const _Float16* __restrict__ Agh, const _Float16* __restrict__ Agl,
    const _Float16* __restrict__ Bg,
    const float* __restrict__ b0, const float* __restrict__ b1,
    const float* __restrict__ b2, const float* __restrict__ rel,
    _Float16* __restrict__ oq, _Float16* __restrict__ okh,
    _Float16* __restrict__ ovt, float* __restrict__ dOut, int mode)
{
    __shared__ _Float16 smem[12288];        // 24 KB: 3 tiles of 128x32 fp16
    _Float16* Ah = smem;
    _Float16* Al = smem + 4096;
    _Float16* Bh = smem + 8192;

    const int tid = threadIdx.x;
    const int w = tid >> 6, l = tid & 63;
    const int lane15 = l & 15, quad = l >> 4;
    const int rm = (w >> 1) * 64, cn = (w & 1) * 64;
    const size_t r0 = (size_t)blockIdx.y * 128;
    const size_t n0 = (size_t)blockIdx.x * 128;

    const int lrow = l >> 2;
    const int lko  = (l & 3) * 8;
    const int ch0 = 2 * w, ch1 = 2 * w + 1;

    f32x4 acc[4][4] = {};

    for (int ks = 0; ks < 32; ks++) {
        const size_t kofs = (size_t)ks * 32 + lko;
        __syncthreads();
        {
            const size_t ga0 = (r0 + ch0 * 16 + lrow) * 1024 + kofs;
            const size_t ga1 = (r0 + ch1 * 16 + lrow) * 1024 + kofs;
            const size_t gb0 = (n0 + ch0 * 16 + lrow) * 1024 + kofs;
            const size_t gb1 = (n0 + ch1 * 16 + lrow) * 1024 + kofs;
            async_cp16(&Agh[ga0], &Ah[ch0 * 512]);
            async_cp16(&Agh[ga1], &Ah[ch1 * 512]);
            async_cp16(&Agl[ga0], &Al[ch0 * 512]);
            async_cp16(&Agl[ga1], &Al[ch1 * 512]);
            async_cp16(&Bg[gb0],  &Bh[ch0 * 512]);
            async_cp16(&Bg[gb1],  &Bh[ch1 * 512]);
        }
        __syncthreads();

        f16x8 ah[4], al[4], bh4[4];
        #pragma unroll
        for (int ii = 0; ii < 4; ii++) {
            int ro = (rm + ii * 16 + lane15) * 32 + quad * 8;
            ah[ii] = *(const f16x8*)&Ah[ro];
            al[ii] = *(const f16x8*)&Al[ro];
        }
        #pragma unroll
        for (int jj = 0; jj < 4; jj++) {
            int co = (cn + jj * 16 + lane15) * 32 + quad * 8;
            bh4[jj] = *(const f16x8*)&Bh[co];
        }
        #pragma unroll
        for (int ii = 0; ii < 4; ii++)
            #pragma unroll
            for (int jj = 0; jj < 4; jj++) {
                f32x4 c = acc[ii][jj];
                c = __builtin_amdgcn_mfma_f32_16x16x32_f16(ah[ii], bh4[jj], c, 0, 0, 0);
                c = __builtin_amdgcn_mfma_f32_16x16x32_f16(al[ii], bh4[jj], c, 0, 0, 0);
                acc[ii][jj] = c;
            }
    }

    if (mode == 0) {
        const int z = blockIdx.x >> 3;                 // 0=q, 1=k, 2=v
        const float* bias = (z == 0) ? b0 : (z == 1) ? b1 : b2;
        const int nbase = (blockIdx.x & 7) * 128 + cn;
        #pragma unroll
        for (int ii = 0; ii < 4; ii++)
            #pragma unroll
            for (int jj = 0; jj < 4; jj++) {
                int nc = nbase + jj * 16 + lane15;
                int hh = nc >> 6, hd = nc & 63;
                float bsv = bias[nc];
                #pragma unroll
                for (int r = 0; r < 4; r++) {
                    int gr = (int)r0 + rm + ii * 16 + quad * 4 + r;
                    int bb = gr >> 10, s = gr & 1023;
                    float val = acc[ii][jj][r] + bsv;
                    size_t hidx = (((size_t)bb * HH + hh) * SS + s) * HDD + hd;
                    if (z == 0) {
                        oq[hidx] = (_Float16)val;
                    } else if (z == 1) {
                        okh[hidx] = (_Float16)(val * 0.125f + rel[s * HDD + hd]);
                    } else {
                        ovt[(((size_t)bb * HH + hh) * HDD + hd) * SS + s] = (_Float16)val;
                    }
                }
            }
    } else {
        #pragma unroll
        for (int ii = 0; ii < 4; ii++)
            #pragma unroll
            for (int jj = 0; jj < 4; jj++) {
                int nc = (int)n0 + cn + jj * 16 + lane15;
                float bsv = b0[nc];
                #pragma unroll
                for (int r = 0; r < 4; r++) {
                    int gr = (int)r0 + rm + ii * 16 + quad * 4 + r;
                    dOut[(size_t)gr * DD + nc] = acc[ii][jj][r] + bsv;
                }
            }
    }
}

// ---------------------------------------------------------------------------
// MFMA flash attention, fp16. grid = 1024 (id = qt*128 + bh), block = 256.
// Each wave owns 32 query rows (2 m-tiles). Single-term fp16 QK^T.
// ---------------------------------------------------------------------------
__global__ __launch_bounds__(256) void attn_mfma(
    const _Float16* __restrict__ qh, const _Float16* __restrict__ kh,
    const _Float16* __restrict__ vt, const int* __restrict__ mask,
    _Float16* __restrict__ ctxh, _Float16* __restrict__ ctxl)
{
    __shared__ _Float16 Ks[64 * PSTR];   // [key][d]
    __shared__ _Float16 Vs[64 * PSTR];   // [d][key]
    __shared__ _Float16 Ps[128 * PSTR];  // [qrow][key swizzled]

    const int tid = threadIdx.x;
    const int w = tid >> 6, l = tid & 63;
    const int lane15 = l & 15, quad = l >> 4;
    const int id = blockIdx.x;
    const int qt = id >> 7;
    const int bh = id & 127;
    const int b = bh >> 4, h = bh & 15;
    const size_t kbase0 = (size_t)bh * SS;
    const size_t vbase0 = (size_t)bh * HDD;
    const size_t qrow0 = kbase0 + qt * 128 + w * 32;

    // resident Q fragments (A-layout): [mtile][kstep]
    f16x8 qf[2][2];
    #pragma unroll
    for (int mi = 0; mi < 2; mi++)
        #pragma unroll
        for (int ks = 0; ks < 2; ks++)
            qf[mi][ks] = *(const f16x8*)&qh[(qrow0 + mi * 16 + lane15) * HDD + ks * 32 + quad * 8];

    f32x4 O[2][4] = {};
    float m_s[2][4], l_s[2][4];
    #pragma unroll
    for (int mi = 0; mi < 2; mi++)
        #pragma unroll
        for (int r = 0; r < 4; r++) { m_s[mi][r] = -1e30f; l_s[mi][r] = 0.f; }

    for (int kt = 0; kt < 16; kt++) {
        const int t0 = kt * 64;
        __syncthreads();
        #pragma unroll
        for (int rep = 0; rep < 2; rep++) {
            int c = rep * 256 + tid;
            int row = c >> 3, cc = (c & 7) * 8;
            f16x8 tk = *(const f16x8*)&kh[(kbase0 + t0 + row) * HDD + cc];
            f16x8 tv = *(const f16x8*)&vt[(vbase0 + row) * SS + t0 + cc];
            *(f16x8*)&Ks[row * PSTR + cc] = tk;
            *(f16x8*)&Vs[row * PSTR + cc] = tv;
        }
        __syncthreads();

        float madd[4];
        #pragma unroll
        for (int nt = 0; nt < 4; nt++)
            madd[nt] = (mask[b * SS + t0 + nt * 16 + lane15] == 0) ? -1e30f : 0.0f;

        #pragma unroll
        for (int mi = 0; mi < 2; mi++) {
            f32x4 S[4] = {};
            #pragma unroll
            for (int nt = 0; nt < 4; nt++) {
                f16x8 kf0 = *(const f16x8*)&Ks[(nt * 16 + lane15) * PSTR + quad * 8];
                f16x8 kf1 = *(const f16x8*)&Ks[(nt * 16 + lane15) * PSTR + 32 + quad * 8];
                f32x4 c = S[nt];
                c = __builtin_amdgcn_mfma_f32_16x16x32_f16(qf[mi][0], kf0, c, 0, 0, 0);
                c = __builtin_amdgcn_mfma_f32_16x16x32_f16(qf[mi][1], kf1, c, 0, 0, 0);
                S[nt] = c;
            }
            #pragma unroll
            for (int nt = 0; nt < 4; nt++)
                #pragma unroll
                for (int r = 0; r < 4; r++) S[nt][r] += madd[nt];

            float tm[4];
            #pragma unroll
            for (int r = 0; r < 4; r++)
                tm[r] = fmaxf(fmaxf(S[0][r], S[1][r]), fmaxf(S[2][r], S[3][r]));
            #pragma unroll
            for (int st = 1; st < 16; st <<= 1)
                #pragma unroll
                for (int r = 0; r < 4; r++)
                    tm[r] = fmaxf(tm[r], __shfl_xor(tm[r], st, 64));
            float alpha[4];
            #pragma unroll
            for (int r = 0; r < 4; r++) {
                float mn = fmaxf(m_s[mi][r], tm[r]);
                alpha[r] = __expf(m_s[mi][r] - mn);
                m_s[mi][r] = mn;
            }
            float ps[4] = {0.f, 0.f, 0.f, 0.f};
            #pragma unroll
            for (int nt = 0; nt < 4; nt++)
                #pragma unroll
                for (int r = 0; r < 4; r++) {
                    float p = __expf(S[nt][r] - m_s[mi][r]);
                    S[nt][r] = p;
                    ps[r] += p;
                }
            #pragma unroll
            for (int st = 1; st < 16; st <<= 1)
                #pragma unroll
                for (int r = 0; r < 4; r++)
                    ps[r] += __shfl_xor(ps[r], st, 64);
            #pragma unroll
            for (int r = 0; r < 4; r++)
                l_s[mi][r] = l_s[mi][r] * alpha[r] + ps[r];
            #pragma unroll
            for (int nd = 0; nd < 4; nd++)
                #pragma unroll
                for (int r = 0; r < 4; r++) O[mi][nd][r] *= alpha[r];
            // write P (fp16) to wave-private LDS, col rotated by +16*quad
            const int rowb = w * 32 + mi * 16 + quad * 4;
            #pragma unroll
            for (int nt = 0; nt < 4; nt++) {
                int colp = (nt * 16 + lane15 + 16 * quad) & 63;
                #pragma unroll
                for (int r = 0; r < 4; r++)
                    Ps[(rowb + r) * PSTR + colp] = (_Float16)S[nt][r];
            }
        }

        // ---- PV: O += P . V ----
        const int swz = 16 * (lane15 >> 2);
        #pragma unroll
        for (int ks2 = 0; ks2 < 2; ks2++) {
            f16x8 pf[2];
            #pragma unroll
            for (int mi = 0; mi < 2; mi++) {
                int colp = (ks2 * 32 + quad * 8 + swz) & 63;
                pf[mi] = *(const f16x8*)&Ps[(w * 32 + mi * 16 + lane15) * PSTR + colp];
            }
            #pragma unroll
            for (int nd = 0; nd < 4; nd++) {
                f16x8 vf = *(const f16x8*)&Vs[(nd * 16 + lane15) * PSTR + ks2 * 32 + quad * 8];
                #pragma unroll
                for (int mi = 0; mi < 2; mi++)
                    O[mi][nd] = __builtin_amdgcn_mfma_f32_16x16x32_f16(pf[mi], vf, O[mi][nd], 0, 0, 0);
            }
        }
    }

    // ---- epilogue: normalize, split to fp16 hi/lo ctx [B,S,D] ----
    #pragma unroll
    for (int mi = 0; mi < 2; mi++) {
        float linv[4];
        #pragma unroll
        for (int r = 0; r < 4; r++) linv[r] = 1.0f / l_s[mi][r];
        #pragma unroll
        for (int nd = 0; nd < 4; nd++) {
            int d = nd * 16 + lane15;
            #pragma unroll
            for (int r = 0; r < 4; r++) {
                int srow = qt * 128 + w * 32 + mi * 16 + quad * 4 + r;
                float val = O[mi][nd][r] * linv[r];
                _Float16 hi = (_Float16)val;
                size_t idx = ((size_t)b * SS + srow) * DD + h * HDD + d;
                ctxh[idx] = hi;
                ctxl[idx] = (_Float16)(val - (float)hi);
            }
        }
    }
}

extern "C" void kernel_launch(void* const* d_in, const int* in_sizes, int n_in,
                              void* d_out, int out_size, void* d_ws, size_t ws_size,
                              hipStream_t stream) {
    const float* x    = (const float*)d_in[0];
    const float* rel  = (const float*)d_in[1];
    const int*   mask = (const int*)d_in[2];
    const float* Wq = (const float*)d_in[3];  const float* bq = (const float*)d_in[4];
    const float* Wk = (const float*)d_in[5];  const float* bk = (const float*)d_in[6];
    const float* Wv = (const float*)d_in[7];  const float* bv = (const float*)d_in[8];
    const float* Wo = (const float*)d_in[9];  const float* bo = (const float*)d_in[10];
    float* out = (float*)d_out;

    const size_t XN = (size_t)NROW * DD;   // 8,388,608
    char* p = (char*)d_ws;
    _Float16* xh  = (_Float16*)p; p += XN * 2;
    _Float16* xl  = (_Float16*)p; p += XN * 2;
    _Float16* wt  = (_Float16*)p; p += (size_t)3072 * 1024 * 2;
    _Float16* wot = (_Float16*)p; p += (size_t)1024 * 1024 * 2;
    _Float16* qhp = (_Float16*)p; p += XN * 2;
    _Float16* khp = (_Float16*)p; p += XN * 2;
    _Float16* vtp = (_Float16*)p; p += XN * 2;
    // ctx aliases x-split buffers (x dead after qkv gemm)
    _Float16* ctxh = xh;
    _Float16* ctxl = xl;

    conv_x_kernel<<<dim3((unsigned)(XN / 2048)), 256, 0, stream>>>(x, xh, xl);
    conv_w_kernel<<<dim3(16, 16, 4), 256, 0, stream>>>(Wq, Wk, Wv, Wo, wt, wot);
    gemm_split<<<dim3(24, 64), 256, 0, stream>>>(
        xh, xl, wt, bq, bk, bv, rel,
        qhp, khp, vtp, nullptr, 0);
    attn_mfma<<<dim3(1024), 256, 0, stream>>>(
        qhp, khp, vtp, mask, ctxh, ctxl);
    gemm_split<<<dim3(8, 64), 256, 0, stream>>>(
        ctxh, ctxl, wot, bo, nullptr, nullptr, nullptr,
        nullptr, nullptr, nullptr, out, 1);
}

// Round 5
// 363.713 us; speedup vs baseline: 4.6383x; 1.2447x over previous
//
#include <hip/hip_runtime.h>

#define DD 1024
#define HH 16
#define HDD 64
#define BBATCH 8
#define SS 1024
#define NROW (BBATCH*SS)   // 8192
#define PSTR 72            // LDS row stride (halfs) for attn tiles

typedef _Float16 f16x8 __attribute__((ext_vector_type(8)));
typedef _Float16 f16x4 __attribute__((ext_vector_type(4)));
typedef float    f32x4 __attribute__((ext_vector_type(4)));

// ---- async global->LDS 16B ----
__device__ __forceinline__ void async_cp16(const void* g, void* l) {
    __builtin_amdgcn_global_load_lds(
        (const __attribute__((address_space(1))) void*)g,
        (__attribute__((address_space(3))) void*)l, 16, 0, 0);
}

// ---------------------------------------------------------------------------
// Convert x (fp32) -> fp16. 4096 blocks x 256 thr x 8 elems.
// ---------------------------------------------------------------------------
__global__ __launch_bounds__(256) void conv_x_kernel(
    const float* __restrict__ x, _Float16* __restrict__ xh)
{
    size_t i8 = ((size_t)blockIdx.x * 256 + threadIdx.x) * 8;
    float4 v0 = *(const float4*)&x[i8];
    float4 v1 = *(const float4*)&x[i8 + 4];
    float vf[8] = {v0.x, v0.y, v0.z, v0.w, v1.x, v1.y, v1.z, v1.w};
    f16x8 hv;
    #pragma unroll
    for (int c = 0; c < 8; c++) hv[c] = (_Float16)vf[c];
    *(f16x8*)&xh[i8] = hv;
}

// ---------------------------------------------------------------------------
// Transpose + convert weights: W[k][n] fp32 -> Wt[n][k] fp16.
// grid = (16,16,4): z in {Wq,Wk,Wv -> wt rows z*1024, Wo -> wot}.
// ---------------------------------------------------------------------------
__global__ __launch_bounds__(256) void conv_w_kernel(
    const float* __restrict__ Wq, const float* __restrict__ Wk,
    const float* __restrict__ Wv, const float* __restrict__ Wo,
    _Float16* __restrict__ wt, _Float16* __restrict__ wot)
{
    __shared__ float T[64][65];
    const int z = blockIdx.z;
    const float* src = (z == 0) ? Wq : (z == 1) ? Wk : (z == 2) ? Wv : Wo;
    _Float16* dh = (z < 3) ? wt + (size_t)z * 1024 * 1024 : wot;
    const int k0 = blockIdx.x * 64, n0 = blockIdx.y * 64;
    const int tid = threadIdx.x;

    #pragma unroll
    for (int rep = 0; rep < 4; rep++) {
        int e = rep * 256 + tid;
        int kr = e >> 4, nc = (e & 15) * 4;
        *(float4*)&T[kr][nc] = *(const float4*)&src[(size_t)(k0 + kr) * 1024 + n0 + nc];
    }
    __syncthreads();
    #pragma unroll
    for (int rep = 0; rep < 4; rep++) {
        int e = rep * 256 + tid;
        int nr = e >> 4, kc = (e & 15) * 4;
        f16x4 hv;
        #pragma unroll
        for (int c = 0; c < 4; c++) hv[c] = (_Float16)T[kc + c][nr];
        *(f16x4*)&dh[(size_t)(n0 + nr) * 1024 + k0 + kc] = hv;
    }
}

// ---------------------------------------------------------------------------
// fp16 MFMA GEMM, 128x128 tile, BK=32 (m97 structure): C = A·B^T.
// mode 0: qkv — A = xh, B = wt[3072][1024]; epilogue: q fp16,
//          k' = (acc+bk)*scale+rel fp16, v transposed [B,H,HD,S] fp16.
// mode 1: out — A = ctx fp16, B = wot; epilogue: d_out fp32 + bo.
// ---------------------------------------------------------------------------
__global__ __launch_bounds__(256) void gemm_f16(
    const _Float16* __restrict__ Ag, const _Float16* __restrict__ Bg,
    const float* __restrict__ b0, const float* __restrict__ b1,
    const float* __restrict__ b2, const float* __restrict__ rel,
    _Float16* __restrict__ oq, _Float16* __restrict__ okh,
    _Float16* __restrict__ ovt, float* __restrict__ dOut, int mode)
{
    __shared__ _Float16 smem[8192];         // 16 KB: A,B tiles 128x32 fp16
    _Float16* Ah = smem;
    _Float16* Bh = smem + 4096;

    const int tid = threadIdx.x;
    const int w = tid >> 6, l = tid & 63;
    const int lane15 = l & 15, quad = l >> 4;
    const int rm = (w >> 1) * 64, cn = (w & 1) * 64;
    const size_t r0 = (size_t)blockIdx.y * 128;
    const size_t n0 = (size_t)blockIdx.x * 128;

    const int lrow = l >> 2;
    const int lko  = (l & 3) * 8;
    const int ch0 = 2 * w, ch1 = 2 * w + 1;

    f32x4 acc[4][4] = {};

    for (int ks = 0; ks < 32; ks++) {
        const size_t kofs = (size_t)ks * 32 + lko;
        __syncthreads();
        {
            const size_t ga0 = (r0 + ch0 * 16 + lrow) * 1024 + kofs;
            const size_t ga1 = (r0 + ch1 * 16 + lrow) * 1024 + kofs;
            const size_t gb0 = (n0 + ch0 * 16 + lrow) * 1024 + kofs;
            const size_t gb1 = (n0 + ch1 * 16 + lrow) * 1024 + kofs;
            async_cp16(&Ag[ga0], &Ah[ch0 * 512]);
            async_cp16(&Ag[ga1], &Ah[ch1 * 512]);
            async_cp16(&Bg[gb0], &Bh[ch0 * 512]);
            async_cp16(&Bg[gb1], &Bh[ch1 * 512]);
        }
        __syncthreads();

        f16x8 ah[4], bh4[4];
        #pragma unroll
        for (int ii = 0; ii < 4; ii++)
            ah[ii] = *(const f16x8*)&Ah[(rm + ii * 16 + lane15) * 32 + quad * 8];
        #pragma unroll
        for (int jj = 0; jj < 4; jj++)
            bh4[jj] = *(const f16x8*)&Bh[(cn + jj * 16 + lane15) * 32 + quad * 8];
        #pragma unroll
        for (int ii = 0; ii < 4; ii++)
            #pragma unroll
            for (int jj = 0; jj < 4; jj++)
                acc[ii][jj] = __builtin_amdgcn_mfma_f32_16x16x32_f16(
                    ah[ii], bh4[jj], acc[ii][jj], 0, 0, 0);
    }

    if (mode == 0) {
        const int z = blockIdx.x >> 3;                 // 0=q, 1=k, 2=v
        const float* bias = (z == 0) ? b0 : (z == 1) ? b1 : b2;
        const int nbase = (blockIdx.x & 7) * 128 + cn;
        #pragma unroll
        for (int ii = 0; ii < 4; ii++)
            #pragma unroll
            for (int jj = 0; jj < 4; jj++) {
                int nc = nbase + jj * 16 + lane15;
                int hh = nc >> 6, hd = nc & 63;
                float bsv = bias[nc];
                #pragma unroll
                for (int r = 0; r < 4; r++) {
                    int gr = (int)r0 + rm + ii * 16 + quad * 4 + r;
                    int bb = gr >> 10, s = gr & 1023;
                    float val = acc[ii][jj][r] + bsv;
                    size_t hidx = (((size_t)bb * HH + hh) * SS + s) * HDD + hd;
                    if (z == 0) {
                        oq[hidx] = (_Float16)val;
                    } else if (z == 1) {
                        okh[hidx] = (_Float16)(val * 0.125f + rel[s * HDD + hd]);
                    } else {
                        ovt[(((size_t)bb * HH + hh) * HDD + hd) * SS + s] = (_Float16)val;
                    }
                }
            }
    } else {
        #pragma unroll
        for (int ii = 0; ii < 4; ii++)
            #pragma unroll
            for (int jj = 0; jj < 4; jj++) {
                int nc = (int)n0 + cn + jj * 16 + lane15;
                float bsv = b0[nc];
                #pragma unroll
                for (int r = 0; r < 4; r++) {
                    int gr = (int)r0 + rm + ii * 16 + quad * 4 + r;
                    dOut[(size_t)gr * DD + nc] = acc[ii][jj][r] + bsv;
                }
            }
    }
}

// ---------------------------------------------------------------------------
// MFMA flash attention, fp16, latency-optimized.
// grid = 1024 (id = qt*128 + bh), block = 512 (8 waves, 16 q-rows each).
// Register double-buffer prefetch of K/V tiles; mask bias staged in LDS once.
// ---------------------------------------------------------------------------
__global__ __launch_bounds__(512, 6) void attn_mfma(
    const _Float16* __restrict__ qh, const _Float16* __restrict__ kh,
    const _Float16* __restrict__ vt, const int* __restrict__ mask,
    _Float16* __restrict__ ctx)
{
    __shared__ _Float16 Ks[64 * PSTR];    // [key][d]      9216 B
    __shared__ _Float16 Vs[64 * PSTR];    // [d][key]      9216 B
    __shared__ _Float16 Ps[128 * PSTR];   // [qrow][key]  18432 B
    __shared__ float maddL[1024];         //               4096 B  -> 40960 B total

    const int tid = threadIdx.x;          // 0..511
    const int w = tid >> 6, l = tid & 63;
    const int lane15 = l & 15, quad = l >> 4;
    const int id = blockIdx.x;
    const int qt = id >> 7;               // 0..7
    const int bh = id & 127;
    const int b = bh >> 4, h = bh & 15;
    const size_t kbase0 = (size_t)bh * SS;
    const size_t vbase0 = (size_t)bh * HDD;
    const size_t qrow0 = kbase0 + qt * 128 + w * 16;

    // mask bias -> LDS once (removes per-kt dependent global loads)
    #pragma unroll
    for (int i = tid; i < 1024; i += 512)
        maddL[i] = (mask[b * SS + i] == 0) ? -1e30f : 0.0f;

    // resident Q fragments (A-layout): [kstep]
    f16x8 qf[2];
    #pragma unroll
    for (int ks = 0; ks < 2; ks++)
        qf[ks] = *(const f16x8*)&qh[(qrow0 + lane15) * HDD + ks * 32 + quad * 8];

    f32x4 O[4] = {};
    float m_s[4], l_s[4];
    #pragma unroll
    for (int r = 0; r < 4; r++) { m_s[r] = -1e30f; l_s[r] = 0.f; }

    // staging: 512 threads x one 16B chunk each for K and V
    const int grow = tid >> 3;            // 0..63
    const int gcc  = (tid & 7) * 8;       // 0..56 halfs
    const _Float16* kp = &kh[(kbase0 + grow) * HDD + gcc];
    const _Float16* vp = &vt[(vbase0 + grow) * SS + gcc];
    f16x8 kreg = *(const f16x8*)kp;       // prefetch kt=0
    f16x8 vreg = *(const f16x8*)vp;

    for (int kt = 0; kt < 16; kt++) {
        // stage current regs into LDS
        *(f16x8*)&Ks[grow * PSTR + gcc] = kreg;
        *(f16x8*)&Vs[grow * PSTR + gcc] = vreg;
        __syncthreads();
        // prefetch next tile (latency hidden behind compute below)
        if (kt < 15) {
            kreg = *(const f16x8*)(kp + (size_t)(kt + 1) * 64 * HDD);
            vreg = *(const f16x8*)(vp + (size_t)(kt + 1) * 64);
        }
        const int t0 = kt * 64;

        // ---- scores: 16 q-rows x 64 keys ----
        f32x4 S[4];
        #pragma unroll
        for (int nt = 0; nt < 4; nt++) {
            f16x8 kf0 = *(const f16x8*)&Ks[(nt * 16 + lane15) * PSTR + quad * 8];
            f16x8 kf1 = *(const f16x8*)&Ks[(nt * 16 + lane15) * PSTR + 32 + quad * 8];
            f32x4 c = {};
            c = __builtin_amdgcn_mfma_f32_16x16x32_f16(qf[0], kf0, c, 0, 0, 0);
            c = __builtin_amdgcn_mfma_f32_16x16x32_f16(qf[1], kf1, c, 0, 0, 0);
            S[nt] = c;
        }
        #pragma unroll
        for (int nt = 0; nt < 4; nt++) {
            float madd = maddL[t0 + nt * 16 + lane15];
            #pragma unroll
            for (int r = 0; r < 4; r++) S[nt][r] += madd;
        }

        // ---- online softmax (rows = quad*4+r, cols = lane15) ----
        float tm[4];
        #pragma unroll
        for (int r = 0; r < 4; r++)
            tm[r] = fmaxf(fmaxf(S[0][r], S[1][r]), fmaxf(S[2][r], S[3][r]));
        #pragma unroll
        for (int st = 1; st < 16; st <<= 1)
            #pragma unroll
            for (int r = 0; r < 4; r++)
                tm[r] = fmaxf(tm[r], __shfl_xor(tm[r], st, 64));
        float alpha[4];
        #pragma unroll
        for (int r = 0; r < 4; r++) {
            float mn = fmaxf(m_s[r], tm[r]);
            alpha[r] = __expf(m_s[r] - mn);
            m_s[r] = mn;
        }
        float ps[4] = {0.f, 0.f, 0.f, 0.f};
        #pragma unroll
        for (int nt = 0; nt < 4; nt++)
            #pragma unroll
            for (int r = 0; r < 4; r++) {
                float p = __expf(S[nt][r] - m_s[r]);
                S[nt][r] = p;
                ps[r] += p;
            }
        #pragma unroll
        for (int st = 1; st < 16; st <<= 1)
            #pragma unroll
            for (int r = 0; r < 4; r++)
                ps[r] += __shfl_xor(ps[r], st, 64);
        #pragma unroll
        for (int r = 0; r < 4; r++)
            l_s[r] = l_s[r] * alpha[r] + ps[r];
        #pragma unroll
        for (int nd = 0; nd < 4; nd++)
            #pragma unroll
            for (int r = 0; r < 4; r++) O[nd][r] *= alpha[r];

        // ---- P (fp16) -> wave-private LDS rows, col rotated by +16*quad ----
        const int rowb = w * 16 + quad * 4;
        #pragma unroll
        for (int nt = 0; nt < 4; nt++) {
            int colp = (nt * 16 + lane15 + 16 * quad) & 63;
            #pragma unroll
            for (int r = 0; r < 4; r++)
                Ps[(rowb + r) * PSTR + colp] = (_Float16)S[nt][r];
        }

        // ---- PV: O += P . V ----
        const int swz = 16 * (lane15 >> 2);
        #pragma unroll
        for (int ks2 = 0; ks2 < 2; ks2++) {
            int colp = (ks2 * 32 + quad * 8 + swz) & 63;
            f16x8 pf = *(const f16x8*)&Ps[(w * 16 + lane15) * PSTR + colp];
            #pragma unroll
            for (int nd = 0; nd < 4; nd++) {
                f16x8 vf = *(const f16x8*)&Vs[(nd * 16 + lane15) * PSTR + ks2 * 32 + quad * 8];
                O[nd] = __builtin_amdgcn_mfma_f32_16x16x32_f16(pf, vf, O[nd], 0, 0, 0);
            }
        }
        __syncthreads();   // all waves done with Ks/Vs before next store
    }

    // ---- epilogue: normalize, fp16 ctx [B,S,D] ----
    float linv[4];
    #pragma unroll
    for (int r = 0; r < 4; r++) linv[r] = 1.0f / l_s[r];
    #pragma unroll
    for (int nd = 0; nd < 4; nd++) {
        int d = nd * 16 + lane15;
        #pragma unroll
        for (int r = 0; r < 4; r++) {
            int qrow = qt * 128 + w * 16 + quad * 4 + r;
            ctx[((size_t)b * SS + qrow) * DD + h * HDD + d] =
                (_Float16)(O[nd][r] * linv[r]);
        }
    }
}

extern "C" void kernel_launch(void* const* d_in, const int* in_sizes, int n_in,
                              void* d_out, int out_size, void* d_ws, size_t ws_size,
                              hipStream_t stream) {
    const float* x    = (const float*)d_in[0];
    const float* rel  = (const float*)d_in[1];
    const int*   mask = (const int*)d_in[2];
    const float* Wq = (const float*)d_in[3];  const float* bq = (const float*)d_in[4];
    const float* Wk = (const float*)d_in[5];  const float* bk = (const float*)d_in[6];
    const float* Wv = (const float*)d_in[7];  const float* bv = (const float*)d_in[8];
    const float* Wo = (const float*)d_in[9];  const float* bo = (const float*)d_in[10];
    float* out = (float*)d_out;

    const size_t XN = (size_t)NROW * DD;   // 8,388,608
    char* p = (char*)d_ws;
    _Float16* xh  = (_Float16*)p; p += XN * 2;
    _Float16* wt  = (_Float16*)p; p += (size_t)3072 * 1024 * 2;
    _Float16* wot = (_Float16*)p; p += (size_t)1024 * 1024 * 2;
    _Float16* qhp = (_Float16*)p; p += XN * 2;
    _Float16* khp = (_Float16*)p; p += XN * 2;
    _Float16* vtp = (_Float16*)p; p += XN * 2;
    // ctx aliases xh (x dead after qkv gemm)
    _Float16* ctx = xh;

    conv_x_kernel<<<dim3((unsigned)(XN / 2048)), 256, 0, stream>>>(x, xh);
    conv_w_kernel<<<dim3(16, 16, 4), 256, 0, stream>>>(Wq, Wk, Wv, Wo, wt, wot);
    gemm_f16<<<dim3(24, 64), 256, 0, stream>>>(
        xh, wt, bq, bk, bv, rel, qhp, khp, vtp, nullptr, 0);
    attn_mfma<<<dim3(1024), 512, 0, stream>>>(
        qhp, khp, vtp, mask, ctx);
    gemm_f16<<<dim3(8, 64), 256, 0, stream>>>(
        ctx, wot, bo, nullptr, nullptr, nullptr,
        nullptr, nullptr, nullptr, out, 1);
}